// Round 5
// baseline (275.454 us; speedup 1.0000x reference)
//
#include <hip/hip_runtime.h>
#include <math.h>

#define H_DIM 2880
#define E_NUM 32
#define TOPK 4
#define TT 16        // tokens per block -> grid 1024 = 4 blocks/CU (was 2)
#define KW 96        // k-window per stage
#define NSTG 30      // H_DIM / KW
#define GRP 776      // 8 rows x 96 dw + 8 dw pad (96%32==0, 776%32==8 -> <=2-way banks)
#define XBS 1552     // x buffer: 2 groups (16 rows)
#define WB0 3104     // w buffers start (after 2 x buffers)
#define WBS 3104     // w buffer: 4 groups (32 experts)
#define SMSZ 9312    // 37.25 KiB -> 4 blocks/CU
#define REDR 36
#define LGTO 2304    // logits area after red[4][16][36]

// async global->LDS DMA, 16B/lane; dest = wave-uniform base + lane*16.
#define GLD16(gp, lp)                                                  \
    __builtin_amdgcn_global_load_lds(                                  \
        (const __attribute__((address_space(1))) void*)(gp),           \
        (__attribute__((address_space(3))) void*)(lp), 16, 0, 0)

// R9: occupancy play. rocprof showed gate_fused <110us (absent from top-5;
// harness poison fills ~2x110us dominate dur_us), so kernel ~55us vs ~30us
// HBM floor. Grid was 512 = 2 blocks/CU = 2 waves/SIMD -> correlated barrier
// convoys idle the SIMD. Now: TT=16, grid 1024, NBUF=2, 37.25KB LDS,
// VGPR<=128 via j-outer loop -> 4 blocks/CU = 4 waves/SIMD, independent
// barrier phases. 2-phase counted schedule: issue s+1 AFTER barrier s, drain
// vmcnt(0) at top (loads have a full stage of flight; own-loads only).
//
// Per lane: 4tok x 8exp tile, acc[32]; 16-way k-split ks = wq*4 + ksl,
// lane = ksl*16 + et*4 + tt. Slice of KW=96: dw {ks*4+u,u<4} (b128,16B) +
// {64+ks*2,+1} (b64,8B). DMA: wave wq stages w group wq (3 instr); waves
// 0,1 also stage x groups 0,1 (3 instr). Uneven counts fine: drain is vmcnt(0).
__global__ __launch_bounds__(256, 4) void gate_fused(
    const float* __restrict__ x, const float* __restrict__ w,
    const float* __restrict__ bias, float* __restrict__ out, int T) {
    __shared__ float sm[SMSZ];
    const int tid = threadIdx.x;
    const int lane = tid & 63;
    const int wq = __builtin_amdgcn_readfirstlane(tid >> 6);
    const int tt = lane & 3;            // token group (4 tokens: rows tt*4..+3)
    const int et = (lane >> 2) & 3;     // expert group (8 experts: et*8..+7)
    const int ksl = lane >> 4;          // intra-wave k-slice
    const int t0 = blockIdx.x * TT;

    // DMA pointers. w: all 4 waves, group wq. x: waves 0,1 only, group wq.
    const float* gw[3]; int lw[3];
    const float* gx[3]; int lx[3];
#pragma unroll
    for (int i = 0; i < 3; ++i) {
        const int d = i * 256 + lane * 4;   // dw within 768-dw group
        const int r = d / KW, kk = d % KW;  // row, k-offset (4|96: no straddle)
        gw[i] = w + (size_t)(wq * 8 + r) * H_DIM + kk;
        lw[i] = WB0 + wq * GRP + d;
        const int xr = (wq & 1) * 8 + r;    // wq<2 only; mask keeps ptr in-bounds
        gx[i] = x + (size_t)(t0 + xr) * H_DIM + kk;
        lx[i] = (wq & 1) * GRP + d;
    }

    float acc[32];
#pragma unroll
    for (int i = 0; i < 32; ++i) acc[i] = 0.f;

    // prologue: stage 0 -> buffer 0
#pragma unroll
    for (int i = 0; i < 3; ++i) GLD16(gw[i], &sm[lw[i]]);
    if (wq < 2) {
#pragma unroll
        for (int i = 0; i < 3; ++i) GLD16(gx[i], &sm[lx[i]]);
    }

    const int ks = wq * 4 + ksl;
    const int koA = ks * 4;        // b128 unit, 16-B aligned
    const int koB = 64 + ks * 2;   // b64 unit, 8-B aligned
    // lane-const LDS read bases (dw)
    const int xln = (tt >> 1) * GRP + (tt & 1) * (4 * KW);  // 4-row block base
    const int wln = et * GRP;                               // expert-group base

    for (int s = 0; s < NSTG; ++s) {
        // own stage-s loads issued one full compute-phase ago
        asm volatile("s_waitcnt vmcnt(0)" ::: "memory");
        __builtin_amdgcn_s_barrier();   // all waves: data resident, buf^1 free
        asm volatile("" ::: "memory");

        if (s + 1 < NSTG) {             // prefetch s+1 -> other buffer
            const size_t go = (size_t)(s + 1) * KW;
            const int b = (s + 1) & 1;
#pragma unroll
            for (int i = 0; i < 3; ++i) GLD16(gw[i] + go, &sm[lw[i] + b * WBS]);
            if (wq < 2) {
#pragma unroll
                for (int i = 0; i < 3; ++i) GLD16(gx[i] + go, &sm[lx[i] + b * XBS]);
            }
        }

        const int p = s & 1;
        const float* xb = &sm[p * XBS + xln];
        const float* wb = &sm[WB0 + p * WBS + wln];

        float4 xa[4]; float2 xc[4];
#pragma unroll
        for (int i = 0; i < 4; ++i) xa[i] = *(const float4*)(xb + i * KW + koA);
#pragma unroll
        for (int i = 0; i < 4; ++i) xc[i] = *(const float2*)(xb + i * KW + koB);
#pragma unroll
        for (int j = 0; j < 8; ++j) {
            const float4 wv = *(const float4*)(wb + j * KW + koA);
            const float2 wc = *(const float2*)(wb + j * KW + koB);
#pragma unroll
            for (int i = 0; i < 4; ++i)
                acc[i * 8 + j] += xa[i].x * wv.x + xa[i].y * wv.y +
                                  xa[i].z * wv.z + xa[i].w * wv.w +
                                  xc[i].x * wc.x + xc[i].y * wc.y;
        }
    }

    __syncthreads();  // all compute + DMA done; LDS safe to repurpose

    // fold intra-wave k-slices: lanes l, l^16, l^32 share (tt,et)
#pragma unroll
    for (int d = 0; d < 32; ++d) {
        acc[d] += __shfl_xor(acc[d], 16, 64);
        acc[d] += __shfl_xor(acc[d], 32, 64);
    }

    // lanes 0-15 (ksl==0) park wave partial: red[wq][tok][e] (stride 36)
    if (ksl == 0) {
#pragma unroll
        for (int i = 0; i < 4; ++i) {
            float* rp = &sm[wq * (TT * REDR) + (tt * 4 + i) * REDR + et * 8];
            *(float4*)(rp + 0) = make_float4(acc[i * 8 + 0], acc[i * 8 + 1],
                                             acc[i * 8 + 2], acc[i * 8 + 3]);
            *(float4*)(rp + 4) = make_float4(acc[i * 8 + 4], acc[i * 8 + 5],
                                             acc[i * 8 + 6], acc[i * 8 + 7]);
        }
    }
    __syncthreads();

    // sum 4 wave partials + bias: 128 threads -> 4 logits each
    if (tid < 128) {
        const int tok = tid >> 3, e4 = (tid & 7) * 4;
        float4 sg = *(const float4*)(bias + e4);
#pragma unroll
        for (int q = 0; q < 4; ++q) {
            float4 v = *(const float4*)&sm[q * (TT * REDR) + tok * REDR + e4];
            sg.x += v.x; sg.y += v.y; sg.z += v.z; sg.w += v.w;
        }
        *(float4*)&sm[LGTO + tok * REDR + e4] = sg;
    }
    __syncthreads();

    // first 16 lanes: per-token top-4 + softmax + store
    if (tid < TT) {
        const int t = t0 + tid;
        float logit[E_NUM];
#pragma unroll
        for (int j = 0; j < 8; ++j) {
            float4 v = *(const float4*)&sm[LGTO + tid * REDR + j * 4];
            logit[j * 4] = v.x; logit[j * 4 + 1] = v.y;
            logit[j * 4 + 2] = v.z; logit[j * 4 + 3] = v.w;
        }

        // top-4 descending, ties -> lowest index (strict >, ascending scan)
        int idx[TOPK];
        float val[TOPK];
#pragma unroll
        for (int k = 0; k < TOPK; ++k) {
            float best = -INFINITY;
            int bi = 0;
#pragma unroll
            for (int e = 0; e < E_NUM; ++e) {
                bool taken = false;
                for (int p2 = 0; p2 < k; ++p2) taken = taken || (idx[p2] == e);
                float v = logit[e];
                if (!taken && v > best) { best = v; bi = e; }
            }
            idx[k] = bi;
            val[k] = best;
        }
        float ex[TOPK], ssum = 0.f;
#pragma unroll
        for (int k = 0; k < TOPK; ++k) { ex[k] = expf(val[k] - val[0]); ssum += ex[k]; }
        const float inv = 1.f / ssum;

        *(float4*)(out + (size_t)t * 4) =
            make_float4((float)idx[0], (float)idx[1], (float)idx[2], (float)idx[3]);
        *(float4*)(out + (size_t)T * 4 + (size_t)t * 4) =
            make_float4(ex[0] * inv, ex[1] * inv, ex[2] * inv, ex[3] * inv);
    }
}

extern "C" void kernel_launch(void* const* d_in, const int* in_sizes, int n_in,
                              void* d_out, int out_size, void* d_ws, size_t ws_size,
                              hipStream_t stream) {
    const float* x    = (const float*)d_in[0];  // [B,S,H] fp32
    const float* w    = (const float*)d_in[1];  // [E,H] fp32
    const float* bias = (const float*)d_in[2];  // [E] fp32
    float* out = (float*)d_out;

    const int T = in_sizes[0] / H_DIM;  // 16384

    gate_fused<<<dim3(T / TT), 256, 0, stream>>>(x, w, bias, out, T);
}